// Round 1
// baseline (4082.923 us; speedup 1.0000x reference)
//
#include <hip/hip_runtime.h>

// NDDE forward-Euler DDE solver, d=512, N=2000 sequential steps.
// Persistent kernel: 32 WGs x 256 threads. WG g owns rows [16g,16g+16).
// Weights live in VGPRs (16 float4 per thread). Every step: all-to-all x
// exchange through a ring of tagged 8B records in d_ws, accessed with
// agent-scope atomics (coherent at MALL across XCDs). Tag+data share one
// aligned 8B word -> no fences needed, poison 0xAA.. never matches a tag.

#define D     512
#define NTAU  100
#define NWG   32
#define NT    256
#define RING  128   // ring columns; reuse distance 128 > delay span 102

__device__ __forceinline__ float lo_f(unsigned long long v){
    union { unsigned u; float f; } c; c.u = (unsigned)v; return c.f;
}
__device__ __forceinline__ unsigned long long pack_rec(unsigned tag, float x){
    union { unsigned u; float f; } c; c.f = x;
    return ((unsigned long long)tag << 32) | (unsigned long long)c.u;
}

__global__ __launch_bounds__(NT) void ndde_persistent(
    const float* __restrict__ x0,
    const float* __restrict__ taup,
    const float* __restrict__ W1,
    const float* __restrict__ W2,
    const float* __restrict__ bb,
    const int*   __restrict__ Np,
    float*       __restrict__ out,
    unsigned long long* __restrict__ ring)
{
    const int   N  = Np[0];
    const float dt = 0.01f * taup[0];
    const int g    = blockIdx.x;      // 0..31
    const int tid  = threadIdx.x;     // 0..255
    const int lane = tid & 63;
    const int wv   = tid >> 6;        // wave = row-group of 4 rows
    const int cc   = lane;            // k-chunk index 0..63
    const int rowbase = g * 16 + wv * 4;

    // double-buffered broadcast vector [x(512) | y(512)]; parity by step
    __shared__ __align__(16) float vsh[2][1032];

    // ---- weights into registers: 4 rows x 16 cols per thread ----
    float4 w1a[4], w1b[4], w2a[4], w2b[4];
    #pragma unroll
    for (int r = 0; r < 4; ++r){
        const int row = rowbase + r;
        const float4* r1 = (const float4*)(W1 + (size_t)row * D);
        const float4* r2 = (const float4*)(W2 + (size_t)row * D);
        w1a[r] = r1[cc];        // W1[row][4cc .. 4cc+3]
        w1b[r] = r1[64 + cc];   // W1[row][256+4cc ..]
        w2a[r] = r2[cc];
        w2b[r] = r2[64 + cc];
    }

    // ---- per-row integrator state lives in lanes 0..3 of each wave ----
    const int myrow = rowbase + (lane & 3);
    float xloc = 0.f, bval = 0.f;
    if (lane < 4){
        xloc = x0[myrow];
        bval = bb[myrow];
        out[(size_t)myrow * (N + 1)] = xloc;                 // column 0
        __hip_atomic_store(&ring[myrow], pack_rec(0u, xloc),
                           __ATOMIC_RELAXED, __HIP_MEMORY_SCOPE_AGENT);
    }

    unsigned long long vy0 = 0, vy1 = 0;
    bool dead = false;

    for (int j = 0; j < N && !dead; ++j){
        const int jy = (j > NTAU) ? (j - NTAU) : 0;
        unsigned long long* px = ring + (size_t)(j  & (RING - 1)) * D;
        unsigned long long* py = ring + (size_t)(jy & (RING - 1)) * D;
        // y is x0 for steps 0..100: only (re)load it for j<2 (fill both
        // parity buffers) and j>100.
        const bool needy = (j < 2) || (j > NTAU);

        if (needy){  // y column is >=100 steps old: issue early, no spin expected
            vy0 = __hip_atomic_load(py + tid,       __ATOMIC_RELAXED, __HIP_MEMORY_SCOPE_AGENT);
            vy1 = __hip_atomic_load(py + tid + 256, __ATOMIC_RELAXED, __HIP_MEMORY_SCOPE_AGENT);
        }

        // ---- spin for x_j: wave polls its 128 of the 512 records ----
        unsigned long long vx0, vx1;
        int guard = 1 << 22;
        for (;;){
            vx0 = __hip_atomic_load(px + tid,       __ATOMIC_RELAXED, __HIP_MEMORY_SCOPE_AGENT);
            vx1 = __hip_atomic_load(px + tid + 256, __ATOMIC_RELAXED, __HIP_MEMORY_SCOPE_AGENT);
            const bool ok = ((unsigned)(vx0 >> 32) == (unsigned)j) &&
                            ((unsigned)(vx1 >> 32) == (unsigned)j);
            if (__all(ok)) break;
            if (--guard == 0){ dead = true; break; }   // failsafe vs. hang
        }
        if (needy){
            int gy = 1 << 22;
            while (!__all(((unsigned)(vy0 >> 32) == (unsigned)jy) &&
                          ((unsigned)(vy1 >> 32) == (unsigned)jy))){
                vy0 = __hip_atomic_load(py + tid,       __ATOMIC_RELAXED, __HIP_MEMORY_SCOPE_AGENT);
                vy1 = __hip_atomic_load(py + tid + 256, __ATOMIC_RELAXED, __HIP_MEMORY_SCOPE_AGENT);
                if (--gy == 0){ dead = true; break; }
            }
        }

        // ---- broadcast to LDS (parity buffer removes write/read race) ----
        float* v = vsh[j & 1];
        v[tid]       = lo_f(vx0);
        v[tid + 256] = lo_f(vx1);
        if (needy){
            v[512 + tid]       = lo_f(vy0);
            v[512 + tid + 256] = lo_f(vy1);
        }
        __syncthreads();

        // ---- 4-row partial dot: 64 FMAs, LDS reads bank-balanced b128 ----
        const float4* v4 = (const float4*)v;
        const float4 xa = v4[cc];
        const float4 xb = v4[64 + cc];
        const float4 ya = v4[128 + cc];
        const float4 yb = v4[192 + cc];

        float a0 = 0.f, a1 = 0.f, a2 = 0.f, a3 = 0.f;
        #define ROWDOT(acc, r) \
            acc = fmaf(w1a[r].x, xa.x, acc); acc = fmaf(w1a[r].y, xa.y, acc); \
            acc = fmaf(w1a[r].z, xa.z, acc); acc = fmaf(w1a[r].w, xa.w, acc); \
            acc = fmaf(w1b[r].x, xb.x, acc); acc = fmaf(w1b[r].y, xb.y, acc); \
            acc = fmaf(w1b[r].z, xb.z, acc); acc = fmaf(w1b[r].w, xb.w, acc); \
            acc = fmaf(w2a[r].x, ya.x, acc); acc = fmaf(w2a[r].y, ya.y, acc); \
            acc = fmaf(w2a[r].z, ya.z, acc); acc = fmaf(w2a[r].w, ya.w, acc); \
            acc = fmaf(w2b[r].x, yb.x, acc); acc = fmaf(w2b[r].y, yb.y, acc); \
            acc = fmaf(w2b[r].z, yb.z, acc);  acc = fmaf(w2b[r].w, yb.w, acc);
        ROWDOT(a0, 0) ROWDOT(a1, 1) ROWDOT(a2, 2) ROWDOT(a3, 3)
        #undef ROWDOT

        // ---- in-wave butterfly reduction over the 64 k-chunks ----
        #pragma unroll
        for (int off = 32; off >= 1; off >>= 1){
            a0 += __shfl_xor(a0, off, 64);
            a1 += __shfl_xor(a1, off, 64);
            a2 += __shfl_xor(a2, off, 64);
            a3 += __shfl_xor(a3, off, 64);
        }

        // ---- integrate + publish (lanes 0..3 own rows rowbase..rowbase+3) ----
        if (lane < 4){
            const float z  = ((lane == 0) ? a0 : (lane == 1) ? a1
                             : (lane == 2) ? a2 : a3) + bval;
            const float xn = xloc + dt * tanhf(z);
            xloc = xn;
            out[(size_t)myrow * (N + 1) + (j + 1)] = xn;
            __hip_atomic_store(&ring[(size_t)((j + 1) & (RING - 1)) * D + myrow],
                               pack_rec((unsigned)(j + 1), xn),
                               __ATOMIC_RELAXED, __HIP_MEMORY_SCOPE_AGENT);
        }
    }
}

extern "C" void kernel_launch(void* const* d_in, const int* in_sizes, int n_in,
                              void* d_out, int out_size, void* d_ws, size_t ws_size,
                              hipStream_t stream)
{
    const float* x0  = (const float*)d_in[0];
    const float* tau = (const float*)d_in[1];
    const float* W1  = (const float*)d_in[2];
    const float* W2  = (const float*)d_in[3];
    const float* b   = (const float*)d_in[4];
    const int*   Np  = (const int*)  d_in[5];
    // ring needs RING*512*8 = 512 KB of d_ws
    hipLaunchKernelGGL(ndde_persistent, dim3(NWG), dim3(NT), 0, stream,
                       x0, tau, W1, W2, b, Np,
                       (float*)d_out, (unsigned long long*)d_ws);
}